// Round 1
// baseline (399.375 us; speedup 1.0000x reference)
//
#include <hip/hip_runtime.h>
#include <stdint.h>

// MegatronAttention: B=2, S=2048, H=2048, NH=16, DH=128.
// KEY INSIGHT: reference einsum 'bhqk,bhkd->bhkd' sums over q ->
//   values[b,h,k,d] = colsum_q(probs)[b,h,k] * v[b,h,k,d].
// So we never need probs as a matrix, only per-(b,h) column sums of softmax.
// Pipeline: convert->bf16, QKV GEMM (scatter epilogue), l-pass (row sums of
// exp), cs-pass (weighted col sums, fused V scaling), output GEMM.

typedef __bf16 bf16_t;
typedef __bf16 bf16x8v __attribute__((ext_vector_type(8)));
typedef __bf16 bf16x4v __attribute__((ext_vector_type(4)));
typedef float  f32x4v  __attribute__((ext_vector_type(4)));

#define DEVINL __device__ __forceinline__

// async global->LDS DMA, 16B per lane. LDS dest must be wave-uniform base;
// HW writes lane i's data at base + i*16.
DEVINL void gll16(const bf16_t* g, void* lds_wave_uniform_base) {
    __builtin_amdgcn_global_load_lds(
        (__attribute__((address_space(1))) void*)g,
        (__attribute__((address_space(3))) void*)lds_wave_uniform_base,
        16, 0, 0);
}

// ---------------------------------------------------------------- converts
__global__ void conv_x_k(const float* __restrict__ in, bf16_t* __restrict__ out) {
    size_t i = ((size_t)blockIdx.x * 256 + threadIdx.x) * 4;
    float4 v = *reinterpret_cast<const float4*>(in + i);
    bf16x4v o;
    o[0] = (__bf16)v.x; o[1] = (__bf16)v.y; o[2] = (__bf16)v.z; o[3] = (__bf16)v.w;
    *reinterpret_cast<bf16x4v*>(out + i) = o;
}

// out[n][k] = (bf16) in[k][n]   (in: K x N fp32, out: N x K bf16)
__global__ void conv_wT_k(const float* __restrict__ in, bf16_t* __restrict__ out,
                          int K, int N) {
    __shared__ float t[32][33];
    int n0 = blockIdx.x * 32, k0 = blockIdx.y * 32;
    int tx = threadIdx.x & 31, ty = threadIdx.x >> 5;   // ty in 0..7
#pragma unroll
    for (int i = 0; i < 32; i += 8)
        t[ty + i][tx] = in[(size_t)(k0 + ty + i) * N + n0 + tx];
    __syncthreads();
#pragma unroll
    for (int i = 0; i < 32; i += 8)
        out[(size_t)(n0 + ty + i) * K + k0 + tx] = (__bf16)t[tx][ty + i];
}

// ---------------------------------------------------------------- GEMM
// C[M,N] = A[M,K] @ B[N,K]^T, bf16 in, fp32 acc. 128x128 tile, BK=32,
// 256 threads (4 waves, 2x2 of 64x64), 16x16x32 MFMA.
// LDS staging via global_load_lds w=16 with XOR swizzle: slot(row,j),
// content chunk cc = j ^ ((row>>1)&3) -> frag ds_read_b128 is 2-way (free),
// global side stays 64B-coalesced per 4 lanes.
// MODE 0: scatter-write QKV (Q/K head-contig [bh][s][d], V token-major).
// MODE 1: plain fp32 store to out[m*N+n].
template<int MODE, int N, int K>
__launch_bounds__(256, 2)
__global__ void gemm_bt_k(const bf16_t* __restrict__ A, const bf16_t* __restrict__ Bm,
                          float* __restrict__ outF,
                          bf16_t* __restrict__ Qb, bf16_t* __restrict__ Kb,
                          bf16_t* __restrict__ Vb)
{
    __shared__ __align__(16) bf16_t sA[512 * 8];   // 8 KiB
    __shared__ __align__(16) bf16_t sB[512 * 8];
    const int tid  = threadIdx.x;
    const int lane = tid & 63, wave = tid >> 6;
    const int quad = lane >> 4, l15 = lane & 15;
    const int rowBase = blockIdx.y * 128, colBase = blockIdx.x * 128;
    const int wr0 = (wave >> 1) * 64, wc0 = (wave & 1) * 64;

    const bf16_t* gA[2]; const bf16_t* gB[2]; uint32_t loff[2];
#pragma unroll
    for (int r = 0; r < 2; ++r) {
        int s = r * 256 + wave * 64 + lane;
        int row = s >> 2, j = s & 3;
        int cc = j ^ ((row >> 1) & 3);
        gA[r] = A  + (size_t)(rowBase + row) * K + cc * 8;
        gB[r] = Bm + (size_t)(colBase + row) * K + cc * 8;
        loff[r] = (uint32_t)(r * 256 + wave * 64) * 16;
    }
    int aoff[4], boff[4];   // LDS frag offsets in elements (loop-invariant)
#pragma unroll
    for (int t = 0; t < 4; ++t) {
        int m = wr0 + t * 16 + l15;
        aoff[t] = (m * 4 + (quad ^ ((m >> 1) & 3))) * 8;
        int n = wc0 + t * 16 + l15;
        boff[t] = (n * 4 + (quad ^ ((n >> 1) & 3))) * 8;
    }

    f32x4v acc[4][4] = {};
    for (int kt = 0; kt < K / 32; ++kt) {
        __syncthreads();
#pragma unroll
        for (int r = 0; r < 2; ++r) {
            gll16(gA[r] + kt * 32, (char*)sA + loff[r]);
            gll16(gB[r] + kt * 32, (char*)sB + loff[r]);
        }
        __syncthreads();
        bf16x8v av[4], bv[4];
#pragma unroll
        for (int t = 0; t < 4; ++t) av[t] = *reinterpret_cast<const bf16x8v*>(sA + aoff[t]);
#pragma unroll
        for (int t = 0; t < 4; ++t) bv[t] = *reinterpret_cast<const bf16x8v*>(sB + boff[t]);
#pragma unroll
        for (int ti = 0; ti < 4; ++ti)
#pragma unroll
            for (int tj = 0; tj < 4; ++tj)
                acc[ti][tj] = __builtin_amdgcn_mfma_f32_16x16x32_bf16(
                                  av[ti], bv[tj], acc[ti][tj], 0, 0, 0);
    }

#pragma unroll
    for (int ti = 0; ti < 4; ++ti)
#pragma unroll
        for (int tj = 0; tj < 4; ++tj)
#pragma unroll
            for (int r = 0; r < 4; ++r) {
                int m = rowBase + wr0 + ti * 16 + quad * 4 + r;   // C row
                int n = colBase + wc0 + tj * 16 + l15;            // C col
                float v = acc[ti][tj][r];
                if constexpr (MODE == 0) {
                    int b = m >> 11, s = m & 2047;
                    int which = n >> 11, hd = n & 2047;           // uniform per block
                    bf16_t bv16 = (__bf16)v;
                    if (which == 2) {
                        Vb[(size_t)m * 2048 + hd] = bv16;         // token-major
                    } else {
                        size_t idx = ((size_t)((b << 4) + (hd >> 7)) * 2048 + s) * 128
                                     + (hd & 127);
                        if (which == 0) Qb[idx] = bv16; else Kb[idx] = bv16;
                    }
                } else {
                    outF[(size_t)m * N + n] = v;
                }
            }
}

// ---------------------------------------------------------------- attention
// Both attn kernels: 128(q or k rows) x 2048 loop x 128(d) per block,
// full-d tiles staged (sQ,sK = 32 KiB each = exactly 64 KiB).
// Swizzle: slot j within a 256B row: content chunk cc = j ^ (row&7)
// -> frag reads 2-way bank aliasing (free), staging row stays contiguous.

__launch_bounds__(256, 2)
__global__ void attn_l_k(const bf16_t* __restrict__ Qb, const bf16_t* __restrict__ Kb,
                         float* __restrict__ rl)
{
    __shared__ __align__(16) bf16_t sQ[2048 * 8];
    __shared__ __align__(16) bf16_t sK[2048 * 8];
    const int tid  = threadIdx.x;
    const int lane = tid & 63, wave = tid >> 6;
    const int quad = lane >> 4, l15 = lane & 15;
    const int qt = blockIdx.x, bh = blockIdx.y;
    const bf16_t* Qg = Qb + (size_t)bh * 2048 * 128 + (size_t)qt * 128 * 128;
    const bf16_t* Kg = Kb + (size_t)bh * 2048 * 128;
    const int wr0 = (wave >> 1) * 64, wc0 = (wave & 1) * 64;
    const float scale = 0.08838834764831845f;   // 1/sqrt(128)

    int srow[8], scc[8]; uint32_t soff[8];
#pragma unroll
    for (int r = 0; r < 8; ++r) {
        int s = r * 256 + wave * 64 + lane;
        srow[r] = s >> 4; int j = s & 15;
        scc[r] = j ^ (srow[r] & 7);
        soff[r] = (uint32_t)(r * 256 + wave * 64) * 16;
    }
#pragma unroll
    for (int r = 0; r < 8; ++r)
        gll16(Qg + (size_t)srow[r] * 128 + scc[r] * 8, (char*)sQ + soff[r]);

    float lsum[4][4] = {};   // [ti][reg] per-lane partial row sums (4 cols each)
    for (int nt = 0; nt < 16; ++nt) {
        __syncthreads();
#pragma unroll
        for (int r = 0; r < 8; ++r)
            gll16(Kg + (size_t)(nt * 128 + srow[r]) * 128 + scc[r] * 8,
                  (char*)sK + soff[r]);
        __syncthreads();
        f32x4v sc[4][4] = {};
#pragma unroll
        for (int kb = 0; kb < 4; ++kb) {
            bf16x8v av[4], bv[4];
            int ccq = kb * 4 + quad;
#pragma unroll
            for (int t = 0; t < 4; ++t) {
                int m = wr0 + t * 16 + l15;
                av[t] = *reinterpret_cast<const bf16x8v*>(sQ + (m * 16 + (ccq ^ (m & 7))) * 8);
                int n = wc0 + t * 16 + l15;
                bv[t] = *reinterpret_cast<const bf16x8v*>(sK + (n * 16 + (ccq ^ (n & 7))) * 8);
            }
#pragma unroll
            for (int ti = 0; ti < 4; ++ti)
#pragma unroll
                for (int tj = 0; tj < 4; ++tj)
                    sc[ti][tj] = __builtin_amdgcn_mfma_f32_16x16x32_bf16(
                                     av[ti], bv[tj], sc[ti][tj], 0, 0, 0);
        }
#pragma unroll
        for (int ti = 0; ti < 4; ++ti)
#pragma unroll
            for (int r = 0; r < 4; ++r) {
                float e = 0.f;
#pragma unroll
                for (int tj = 0; tj < 4; ++tj) e += __expf(sc[ti][tj][r] * scale);
                lsum[ti][r] += e;
            }
    }
    // cross-lane (16 lanes of quad hold the row's cols), then cross-wave via LDS
    __syncthreads();                      // all sQ reads done; alias it
    float* l_sh = (float*)sQ;
    if (tid < 128) l_sh[tid] = 0.f;
    __syncthreads();
#pragma unroll
    for (int ti = 0; ti < 4; ++ti)
#pragma unroll
        for (int r = 0; r < 4; ++r) {
            float v = lsum[ti][r];
            v += __shfl_xor(v, 1); v += __shfl_xor(v, 2);
            v += __shfl_xor(v, 4); v += __shfl_xor(v, 8);
            if (l15 == 0) atomicAdd(&l_sh[wr0 + ti * 16 + quad * 4 + r], v);
        }
    __syncthreads();
    if (tid < 128) rl[(size_t)bh * 2048 + qt * 128 + tid] = 1.0f / l_sh[tid];
}

__launch_bounds__(256, 2)
__global__ void attn_cs_k(const bf16_t* __restrict__ Qb, const bf16_t* __restrict__ Kb,
                          const float* __restrict__ rl, bf16_t* __restrict__ Vb)
{
    __shared__ __align__(16) bf16_t sQ[2048 * 8];
    __shared__ __align__(16) bf16_t sK[2048 * 8];
    const int tid  = threadIdx.x;
    const int lane = tid & 63, wave = tid >> 6;
    const int quad = lane >> 4, l15 = lane & 15;
    const int kt = blockIdx.x, bh = blockIdx.y;
    const bf16_t* Qg = Qb + (size_t)bh * 2048 * 128;
    const bf16_t* Kg = Kb + (size_t)bh * 2048 * 128 + (size_t)kt * 128 * 128;
    const float* rlg = rl + (size_t)bh * 2048;
    const int wr0 = (wave >> 1) * 64, wc0 = (wave & 1) * 64;
    const float scale = 0.08838834764831845f;

    int srow[8], scc[8]; uint32_t soff[8];
#pragma unroll
    for (int r = 0; r < 8; ++r) {
        int s = r * 256 + wave * 64 + lane;
        srow[r] = s >> 4; int j = s & 15;
        scc[r] = j ^ (srow[r] & 7);
        soff[r] = (uint32_t)(r * 256 + wave * 64) * 16;
    }
#pragma unroll
    for (int r = 0; r < 8; ++r)     // K tile is resident across the q loop
        gll16(Kg + (size_t)srow[r] * 128 + scc[r] * 8, (char*)sK + soff[r]);

    float csum[4] = {};             // [tj] per-lane partial col sums
    for (int qt = 0; qt < 16; ++qt) {
        __syncthreads();
#pragma unroll
        for (int r = 0; r < 8; ++r)
            gll16(Qg + (size_t)(qt * 128 + srow[r]) * 128 + scc[r] * 8,
                  (char*)sQ + soff[r]);
        __syncthreads();
        f32x4v sc[4][4] = {};
#pragma unroll
        for (int kb = 0; kb < 4; ++kb) {
            bf16x8v av[4], bv[4];
            int ccq = kb * 4 + quad;
#pragma unroll
            for (int t = 0; t < 4; ++t) {
                int m = wr0 + t * 16 + l15;                  // q row (A operand)
                av[t] = *reinterpret_cast<const bf16x8v*>(sQ + (m * 16 + (ccq ^ (m & 7))) * 8);
                int n = wc0 + t * 16 + l15;                  // k col (B operand)
                bv[t] = *reinterpret_cast<const bf16x8v*>(sK + (n * 16 + (ccq ^ (n & 7))) * 8);
            }
#pragma unroll
            for (int ti = 0; ti < 4; ++ti)
#pragma unroll
                for (int tj = 0; tj < 4; ++tj)
                    sc[ti][tj] = __builtin_amdgcn_mfma_f32_16x16x32_bf16(
                                     av[ti], bv[tj], sc[ti][tj], 0, 0, 0);
        }
#pragma unroll
        for (int ti = 0; ti < 4; ++ti)
#pragma unroll
            for (int r = 0; r < 4; ++r) {
                float rli = rlg[qt * 128 + wr0 + ti * 16 + quad * 4 + r];
#pragma unroll
                for (int tj = 0; tj < 4; ++tj)
                    csum[tj] += __expf(sc[ti][tj][r] * scale) * rli;
            }
    }
    __syncthreads();                 // sQ dead; alias for cs
    float* cs_sh = (float*)sQ;
    if (tid < 128) cs_sh[tid] = 0.f;
    __syncthreads();
#pragma unroll
    for (int tj = 0; tj < 4; ++tj) {
        float v = csum[tj];
        v += __shfl_xor(v, 16); v += __shfl_xor(v, 32);
        if (quad == 0) atomicAdd(&cs_sh[wc0 + tj * 16 + l15], v);
    }
    __syncthreads();
    // fused: scale this block's disjoint 128x128 V patch in place
    int b = bh >> 4, h = bh & 15;
#pragma unroll
    for (int r = 0; r < 8; ++r) {
        int s = r * 256 + tid;
        int row = s >> 4, jc = s & 15;
        size_t off = ((size_t)(b * 2048 + kt * 128 + row)) * 2048 + h * 128 + jc * 8;
        float csv = cs_sh[row];
        bf16x8v vv = *reinterpret_cast<const bf16x8v*>(Vb + off);
        bf16x8v ov;
#pragma unroll
        for (int i = 0; i < 8; ++i) ov[i] = (__bf16)((float)vv[i] * csv);
        *reinterpret_cast<bf16x8v*>(Vb + off) = ov;
    }
}

// ---------------------------------------------------------------- launch
extern "C" void kernel_launch(void* const* d_in, const int* in_sizes, int n_in,
                              void* d_out, int out_size, void* d_ws, size_t ws_size,
                              hipStream_t stream) {
    (void)in_sizes; (void)n_in; (void)out_size; (void)ws_size;
    const float* x     = (const float*)d_in[0];
    const float* w_qkv = (const float*)d_in[1];
    const float* w_o   = (const float*)d_in[2];
    float* out = (float*)d_out;

    char* w = (char*)d_ws;
    auto alloc = [&](size_t bytes) {
        char* p = w; w += (bytes + 255) & ~(size_t)255; return p;
    };
    bf16_t* Xb    = (bf16_t*)alloc(4096ull * 2048 * 2);   // 16 MiB
    bf16_t* WqkvT = (bf16_t*)alloc(6144ull * 2048 * 2);   // 24 MiB
    bf16_t* WoT   = (bf16_t*)alloc(2048ull * 2048 * 2);   //  8 MiB
    bf16_t* Qb    = (bf16_t*)alloc(32ull * 2048 * 128 * 2); // 16 MiB [bh][s][d]
    bf16_t* Kb    = (bf16_t*)alloc(32ull * 2048 * 128 * 2);
    bf16_t* Vb    = (bf16_t*)alloc(4096ull * 2048 * 2);   // token-major
    float*  rlb   = (float*)alloc(32ull * 2048 * 4);      // 1/l per (bh, q)

    conv_x_k <<<8192, 256, 0, stream>>>(x, Xb);
    conv_wT_k<<<dim3(192, 64), 256, 0, stream>>>(w_qkv, WqkvT, 2048, 6144);
    conv_wT_k<<<dim3(64, 64),  256, 0, stream>>>(w_o,   WoT,   2048, 2048);

    gemm_bt_k<0, 6144, 2048><<<dim3(48, 32), 256, 0, stream>>>(
        Xb, WqkvT, nullptr, Qb, Kb, Vb);

    attn_l_k <<<dim3(16, 32), 256, 0, stream>>>(Qb, Kb, rlb);
    attn_cs_k<<<dim3(16, 32), 256, 0, stream>>>(Qb, Kb, rlb, Vb);

    gemm_bt_k<1, 2048, 2048><<<dim3(16, 32), 256, 0, stream>>>(
        Vb, WoT, out, nullptr, nullptr, nullptr);
}